// Round 7
// baseline (730.389 us; speedup 1.0000x reference)
//
#include <hip/hip_runtime.h>
#include <hip/hip_bf16.h>
#include <stdint.h>

#define N_USER 100000
#define N_ITEM 50000
#define NTOT   150000
#define NEDGE  1200000
#define D      64
#define OUTD   256
#define NEG    0.01f
#define NBLK   586    // ceil(150000/256)
#define LSTR   65     // LDS row stride (floats): 64+1 -> frag reads <=2-way bank alias
#define INITBLK 9375  // NTOT*16/256 exact

typedef __attribute__((ext_vector_type(8))) short short8;
typedef __attribute__((ext_vector_type(4))) float f32x4;

// fp32 -> bf16 (RNE), returns the 16-bit pattern.
__device__ inline ushort f2bf(float x) {
    uint32_t u = __float_as_uint(x);
    u += 0x7fffu + ((u >> 16) & 1u);
    return (ushort)(u >> 16);
}
// x ~= hi + lo with hi,lo bf16. Combined rel error ~2^-17.
__device__ inline void split2(float x, ushort& h, ushort& l) {
    ushort hh = f2bf(x);
    float hf = __uint_as_float(((uint32_t)hh) << 16);
    h = hh;
    l = f2bf(x - hf);
}
// Load 8 contiguous floats, produce hi/lo bf16 fragments.
__device__ inline void split8(const float* p, short8& h8, short8& l8) {
    float4 v0 = *(const float4*)p;
    float4 v1 = *(const float4*)(p + 4);
    float vv[8] = {v0.x, v0.y, v0.z, v0.w, v1.x, v1.y, v1.z, v1.w};
    #pragma unroll
    for (int e = 0; e < 8; e++) {
        ushort h, l;
        split2(vv[e], h, l);
        h8[e] = (short)h; l8[e] = (short)l;
    }
}

// Fused: build E0 = concat(user,item) + write out chunk 0; AND edge histogram.
// (independent work partitioned by blockIdx -> one launch instead of two)
__global__ void k_init_hist(const float* __restrict__ ue, const float* __restrict__ ie,
                            float* __restrict__ E, float* __restrict__ out,
                            const int* __restrict__ row, int* __restrict__ cnt) {
    if (blockIdx.x < INITBLK) {
        int t = blockIdx.x * 256 + threadIdx.x;     // exactly NTOT*16 threads
        int r = t >> 4, q = t & 15;
        const float* src = (r < N_USER) ? (ue + (size_t)r * D)
                                        : (ie + (size_t)(r - N_USER) * D);
        float4 v = *(const float4*)(src + q * 4);
        *(float4*)(E + (size_t)r * D + q * 4) = v;
        *(float4*)(out + (size_t)r * OUTD + q * 4) = v;
    } else {
        int e = (blockIdx.x - INITBLK) * 256 + threadIdx.x;
        if (e < NEDGE) atomicAdd(&cnt[row[e]], 1);
    }
}

// Phase A: per-block (256) partial sums of counts
__global__ void k_scan_a(const int* __restrict__ cnt, int* __restrict__ part) {
    __shared__ int s[4];
    int i = blockIdx.x * 256 + threadIdx.x;
    int v = (i < NTOT) ? cnt[i] : 0;
    for (int off = 32; off; off >>= 1) v += __shfl_down(v, off, 64);
    if ((threadIdx.x & 63) == 0) s[threadIdx.x >> 6] = v;
    __syncthreads();
    if (threadIdx.x == 0) part[blockIdx.x] = s[0] + s[1] + s[2] + s[3];
}

// Phase B: single-block exclusive scan of NBLK partials
__global__ void k_scan_b(int* __restrict__ part) {
    __shared__ int s[1024];
    int t = threadIdx.x;
    int v = (t < NBLK) ? part[t] : 0;
    s[t] = v;
    __syncthreads();
    for (int off = 1; off < 1024; off <<= 1) {
        int x = (t >= off) ? s[t - off] : 0;
        __syncthreads();
        s[t] += x;
        __syncthreads();
    }
    if (t < NBLK) part[t] = s[t] - v;  // exclusive
}

// Phase C: in-block exclusive scan + block base -> offsets and cursor copy
__global__ void k_scan_c(const int* __restrict__ cnt, const int* __restrict__ part,
                         int* __restrict__ offs, int* __restrict__ cur) {
    __shared__ int ws[4];
    int i = blockIdx.x * 256 + threadIdx.x;
    int v = (i < NTOT) ? cnt[i] : 0;
    int lane = threadIdx.x & 63, w = threadIdx.x >> 6;
    int x = v;
    for (int o = 1; o < 64; o <<= 1) {
        int y = __shfl_up(x, o, 64);
        if (lane >= o) x += y;
    }
    if (lane == 63) ws[w] = x;
    __syncthreads();
    int base = part[blockIdx.x];
    for (int k = 0; k < w; k++) base += ws[k];
    int excl = base + x - v;
    if (i < NTOT) { offs[i] = excl; cur[i] = excl; }
    if (i == 0) offs[NTOT] = NEDGE;
}

// Scatter edges into CSR order as fused (col, val) int2 pairs.
__global__ void k_scatter(const int* __restrict__ row, const int* __restrict__ col,
                          const float* __restrict__ val, int* __restrict__ cur,
                          int2* __restrict__ ce) {
    int e = blockIdx.x * blockDim.x + threadIdx.x;
    if (e >= NEDGE) return;
    int r = row[e];
    int p = atomicAdd(&cur[r], 1);
    int2 u;
    u.x = col[e];
    u.y = __float_as_int(val[e]);
    ce[p] = u;
}

// Fused layer: SpMM (phase A) + double-GEMV/lrelu/norm (phase B, MFMA).
//
// Round-7 design: the spmm->rowmv HBM interface (front write+read, E re-read:
// ~115MB/layer) is eliminated by computing the 16-row tile's SpMM directly
// into the LDS tiles the MFMA phase consumes. In-place E update would race
// with other blocks' gathers, so E ping-pongs (read Ecur, write Enx; kernel
// boundary separates layers).
//   Phase A: 16-lane group per row (group = (wave w, kg=lane>>4)), float4
//   per lane (d4=(lane&15)*4): gathers stay 256B-coalesced, 4-way edge ILP
//   -> 16 gathers in flight per wave (4x the old wave-per-row MLP).
//   Phase B: verified round-6 MFMA path (bf16 hi/lo split, 3 passes,
//   weights in registers, C/D layout col=lane&15,row=(lane>>4)*4+reg).
__global__ __launch_bounds__(256) void k_layer(
    const float* __restrict__ Ecur, float* __restrict__ Enx,
    const int* __restrict__ offs, const int2* __restrict__ ce,
    const float* __restrict__ Wf, const float* __restrict__ bfv,
    const float* __restrict__ Wb, const float* __restrict__ bbv,
    float* __restrict__ out, int chunk) {
    __shared__ float sf[16 * LSTR];
    __shared__ float sg[16 * LSTR];
    __shared__ float nrm[16][4];

    int t    = threadIdx.x;
    int lane = t & 63;
    int w    = t >> 6;          // wave id = col-quarter (phase B)
    int cl   = lane & 15;
    int kg   = lane >> 4;
    int r0   = blockIdx.x * 16;

    // Weight fragments (hi/lo) in registers, k = s*32 + kg*8 + e. L1/L2-hot.
    int col = w * 16 + cl;
    short8 wfh0, wfl0, wbh0, wbl0, wfh1, wfl1, wbh1, wbl1;
    split8(Wf + (size_t)col * D +  0 + kg * 8, wfh0, wfl0);
    split8(Wb + (size_t)col * D +  0 + kg * 8, wbh0, wbl0);
    split8(Wf + (size_t)col * D + 32 + kg * 8, wfh1, wfl1);
    split8(Wb + (size_t)col * D + 32 + kg * 8, wbh1, wbl1);
    float bF = bfv[col], bB = bbv[col];

    // ---- Phase A: SpMM for this block's 16 rows, straight into LDS ----
    {
        int row = w * 4 + kg;       // tile row 0..15 owned by this 16-lane group
        int d4  = cl * 4;           // this lane's 4 dims
        int r   = r0 + row;
        float4 ei = *(const float4*)(Ecur + (size_t)r * D + d4);
        float4 a0 = ei;             // +I term
        float4 a1 = {0.f,0.f,0.f,0.f}, a2 = {0.f,0.f,0.f,0.f}, a3 = {0.f,0.f,0.f,0.f};
        int s = offs[r], e = offs[r + 1];
        int p = s;
        for (; p + 4 <= e; p += 4) {
            int2 c0 = ce[p + 0];
            int2 c1 = ce[p + 1];
            int2 c2 = ce[p + 2];
            int2 c3 = ce[p + 3];
            float4 x0 = *(const float4*)(Ecur + (size_t)c0.x * D + d4);
            float4 x1 = *(const float4*)(Ecur + (size_t)c1.x * D + d4);
            float4 x2 = *(const float4*)(Ecur + (size_t)c2.x * D + d4);
            float4 x3 = *(const float4*)(Ecur + (size_t)c3.x * D + d4);
            float v0 = __int_as_float(c0.y), v1 = __int_as_float(c1.y);
            float v2 = __int_as_float(c2.y), v3 = __int_as_float(c3.y);
            a0.x = fmaf(v0, x0.x, a0.x); a0.y = fmaf(v0, x0.y, a0.y);
            a0.z = fmaf(v0, x0.z, a0.z); a0.w = fmaf(v0, x0.w, a0.w);
            a1.x = fmaf(v1, x1.x, a1.x); a1.y = fmaf(v1, x1.y, a1.y);
            a1.z = fmaf(v1, x1.z, a1.z); a1.w = fmaf(v1, x1.w, a1.w);
            a2.x = fmaf(v2, x2.x, a2.x); a2.y = fmaf(v2, x2.y, a2.y);
            a2.z = fmaf(v2, x2.z, a2.z); a2.w = fmaf(v2, x2.w, a2.w);
            a3.x = fmaf(v3, x3.x, a3.x); a3.y = fmaf(v3, x3.y, a3.y);
            a3.z = fmaf(v3, x3.z, a3.z); a3.w = fmaf(v3, x3.w, a3.w);
        }
        for (; p < e; ++p) {
            int2 c = ce[p];
            float v = __int_as_float(c.y);
            float4 x = *(const float4*)(Ecur + (size_t)c.x * D + d4);
            a0.x = fmaf(v, x.x, a0.x); a0.y = fmaf(v, x.y, a0.y);
            a0.z = fmaf(v, x.z, a0.z); a0.w = fmaf(v, x.w, a0.w);
        }
        float4 fr;
        fr.x = (a0.x + a1.x) + (a2.x + a3.x);
        fr.y = (a0.y + a1.y) + (a2.y + a3.y);
        fr.z = (a0.z + a1.z) + (a2.z + a3.z);
        fr.w = (a0.w + a1.w) + (a2.w + a3.w);
        float4 gv;
        gv.x = fr.x * ei.x; gv.y = fr.y * ei.y;
        gv.z = fr.z * ei.z; gv.w = fr.w * ei.w;
        *(float4*)(sf + row * LSTR + d4) = fr;
        *(float4*)(sg + row * LSTR + d4) = gv;
    }
    __syncthreads();

    // ---- Phase B: MFMA double-GEMV + lrelu + norm (round-6 verified) ----
    f32x4 accF = {0.f, 0.f, 0.f, 0.f};
    f32x4 accB = {0.f, 0.f, 0.f, 0.f};
    {
        short8 fh, fl, gh, gl;
        // kstep 0
        split8(sf + cl * LSTR +  0 + kg * 8, fh, fl);
        split8(sg + cl * LSTR +  0 + kg * 8, gh, gl);
        accF = __builtin_amdgcn_mfma_f32_16x16x32_bf16(fh, wfh0, accF, 0, 0, 0);
        accB = __builtin_amdgcn_mfma_f32_16x16x32_bf16(gh, wbh0, accB, 0, 0, 0);
        accF = __builtin_amdgcn_mfma_f32_16x16x32_bf16(fl, wfh0, accF, 0, 0, 0);
        accB = __builtin_amdgcn_mfma_f32_16x16x32_bf16(gl, wbh0, accB, 0, 0, 0);
        accF = __builtin_amdgcn_mfma_f32_16x16x32_bf16(fh, wfl0, accF, 0, 0, 0);
        accB = __builtin_amdgcn_mfma_f32_16x16x32_bf16(gh, wbl0, accB, 0, 0, 0);
        // kstep 1
        split8(sf + cl * LSTR + 32 + kg * 8, fh, fl);
        split8(sg + cl * LSTR + 32 + kg * 8, gh, gl);
        accF = __builtin_amdgcn_mfma_f32_16x16x32_bf16(fh, wfh1, accF, 0, 0, 0);
        accB = __builtin_amdgcn_mfma_f32_16x16x32_bf16(gh, wbh1, accB, 0, 0, 0);
        accF = __builtin_amdgcn_mfma_f32_16x16x32_bf16(fl, wfh1, accF, 0, 0, 0);
        accB = __builtin_amdgcn_mfma_f32_16x16x32_bf16(gl, wbh1, accB, 0, 0, 0);
        accF = __builtin_amdgcn_mfma_f32_16x16x32_bf16(fh, wfl1, accF, 0, 0, 0);
        accB = __builtin_amdgcn_mfma_f32_16x16x32_bf16(gh, wbl1, accB, 0, 0, 0);
    }

    // Epilogue: bias + lrelu + sum, per-row norm across all 64 cols.
    float e4[4], p4[4];
    #pragma unroll
    for (int rg = 0; rg < 4; rg++) {
        float aF = accF[rg] + bF;
        float aB = accB[rg] + bB;
        float vF = (aF > 0.f) ? aF : NEG * aF;
        float vB = (aB > 0.f) ? aB : NEG * aB;
        float e = vF + vB;
        e4[rg] = e;
        float p = e * e;
        p += __shfl_xor(p, 1, 64);
        p += __shfl_xor(p, 2, 64);
        p += __shfl_xor(p, 4, 64);
        p += __shfl_xor(p, 8, 64);   // sum over this wave's 16 cols
        p4[rg] = p;
    }
    if (cl == 0) {
        #pragma unroll
        for (int rg = 0; rg < 4; rg++) nrm[kg * 4 + rg][w] = p4[rg];
    }
    __syncthreads();
    #pragma unroll
    for (int rg = 0; rg < 4; rg++) {
        int row = kg * 4 + rg;
        float4 nv = *(const float4*)&nrm[row][0];
        float nsq = (nv.x + nv.y) + (nv.z + nv.w);
        float inv = 1.0f / fmaxf(sqrtf(nsq), 1e-12f);
        Enx[(size_t)(r0 + row) * D + col] = e4[rg];
        out[(size_t)(r0 + row) * OUTD + (size_t)chunk * D + col] = e4[rg] * inv;
    }
}

extern "C" void kernel_launch(void* const* d_in, const int* in_sizes, int n_in,
                              void* d_out, int out_size, void* d_ws, size_t ws_size,
                              hipStream_t stream) {
    const float* ue   = (const float*)d_in[0];
    const float* ie   = (const float*)d_in[1];
    const int*   erow = (const int*)d_in[2];
    const int*   ecol = (const int*)d_in[3];
    const float* eval = (const float*)d_in[4];
    const float* Wf   = (const float*)d_in[5];
    const float* bfv  = (const float*)d_in[6];
    const float* Wb   = (const float*)d_in[7];
    const float* bbv  = (const float*)d_in[8];
    float* out = (float*)d_out;

    float* E0   = (float*)d_ws;                     // NTOT*D
    float* E1   = E0 + (size_t)NTOT * D;            // NTOT*D (ping-pong)
    int*   cnt  = (int*)(E1 + (size_t)NTOT * D);    // NTOT
    int*   offs = cnt + NTOT;                       // NTOT+1
    int*   cur  = offs + NTOT + 1;                  // NTOT
    int*   part = cur + NTOT;                       // 1024
    int2*  ce   = (int2*)(part + 1024);             // NEDGE int2 (col,val)

    hipMemsetAsync(cnt, 0, NTOT * sizeof(int), stream);
    k_init_hist<<<INITBLK + (NEDGE + 255) / 256, 256, 0, stream>>>(ue, ie, E0, out, erow, cnt);
    k_scan_a<<<NBLK, 256, 0, stream>>>(cnt, part);
    k_scan_b<<<1, 1024, 0, stream>>>(part);
    k_scan_c<<<NBLK, 256, 0, stream>>>(cnt, part, offs, cur);
    k_scatter<<<(NEDGE + 255) / 256, 256, 0, stream>>>(erow, ecol, eval, cur, ce);

    const float* rd[3] = {E0, E1, E0};
    float*       wr[3] = {E1, E0, E1};
    for (int i = 0; i < 3; i++) {
        k_layer<<<NTOT / 16, 256, 0, stream>>>(
            rd[i], wr[i], offs, ce,
            Wf + (size_t)i * D * D, bfv + (size_t)i * D,
            Wb + (size_t)i * D * D, bbv + (size_t)i * D, out, i + 1);
    }
}